// Round 13
// baseline (247.445 us; speedup 1.0000x reference)
//
#include <hip/hip_runtime.h>
#include <math.h>

#define DM   1024
#define LL   4096
#define NB   2
#define E3   3072
#define FPI  3.14159265358979323846f
#define RCQ  0.70710678118654752f

typedef __bf16 bf16x8 __attribute__((ext_vector_type(8)));
typedef float  f32x4  __attribute__((ext_vector_type(4)));
typedef _Float16 f16x2 __attribute__((ext_vector_type(2)));

__device__ __forceinline__ unsigned short f2bf(float x) {
    unsigned u = __float_as_uint(x);
    u += 0x7fffu + ((u >> 16) & 1u);
    return (unsigned short)(u >> 16);
}
__device__ __forceinline__ float bf2f(ushort s) {
    return __uint_as_float(((unsigned)s) << 16);
}
__device__ __forceinline__ void gload16(void* lds, const void* g) {
    typedef const __attribute__((address_space(1))) unsigned int* gp_t;
    typedef __attribute__((address_space(3))) unsigned int* lp_t;
    __builtin_amdgcn_global_load_lds((gp_t)g, (lp_t)lds, 16, 0, 0);
}

// ---------------------------------------------------------------------------
// cvt3: f32 -> bf16 for three arrays in one launch
// ---------------------------------------------------------------------------
__global__ __launch_bounds__(256) void k_cvt3(
    const float* __restrict__ a, ushort* __restrict__ oa, int n4a,
    const float* __restrict__ b, ushort* __restrict__ ob, int n4b,
    const float* __restrict__ c, ushort* __restrict__ oc, int n4c)
{
    int idx = blockIdx.x * 256 + threadIdx.x;
    int stride = gridDim.x * 256;
    int tot = n4a + n4b + n4c;
    for (int i = idx; i < tot; i += stride) {
        const float4* src; ushort* dst; int k;
        if (i < n4a)            { src = (const float4*)a; dst = oa; k = i; }
        else if (i < n4a + n4b) { src = (const float4*)b; dst = ob; k = i - n4a; }
        else                    { src = (const float4*)c; dst = oc; k = i - n4a - n4b; }
        float4 v = src[k];
        ushort4 o;
        o.x = f2bf(v.x); o.y = f2bf(v.y); o.z = f2bf(v.z); o.w = f2bf(v.w);
        *reinterpret_cast<ushort4*>(dst + 4 * k) = o;
    }
}

// ---------------------------------------------------------------------------
// 128x256 4-phase bf16 MFMA GEMM (K=1024), bias PER ROW, writes bf16.
// Up-projection in SWAPPED form: C[e][m] = W[e,:]·u[m,:] + b[e].
// XCD swizzle: each XCD owns a contiguous chunk of Ntiles/8 n-tiles.
// ---------------------------------------------------------------------------
__global__ __launch_bounds__(512, 1) void k_gemm128n(
    const ushort* __restrict__ A, const ushort* __restrict__ B,
    const float* __restrict__ bias, ushort* __restrict__ C,
    int Ntiles, int ldc)
{
    __shared__ __align__(16) char ldsm[98304];
    const int tid  = threadIdx.x;
    const int lane = tid & 63;
    const int w    = tid >> 6;
    const int wr   = w >> 2, wc = w & 3;

    const int nch = Ntiles >> 3;
    const int xcd = blockIdx.x & 7;
    const int loc = blockIdx.x >> 3;
    const int n0 = ((xcd * nch) + (loc % nch)) << 8;
    const int m0 = (loc / nch) << 7;

    const int r0 = tid >> 2;
    const int swzc = ((tid & 3) ^ ((r0 >> 1) & 3)) << 4;
    const char* Asrc = (const char*)A + ((size_t)(m0 + r0) << 11) + swzc;
    const char* Bsrc = (const char*)B + ((size_t)(n0 + r0) << 11) + swzc;
    char* Ld = ldsm + tid * 16;

    const int lm = lane & 15, lk = lane >> 4;
    const int rA = wr * 64 + lm;
    const int rB = wc * 64 + lm;
    const int aBase = rA * 64 + ((lk ^ ((rA >> 1) & 3)) << 4);
    const int bBase = 16384 + rB * 64 + ((lk ^ ((rB >> 1) & 3)) << 4);

#define STG_A(ks, nb, t1) \
    gload16(Ld + (nb) + (ks)*8192, Asrc + (t1)*128 + (ks)*64)
#define STG_B(ks, nb, t1) do { \
    gload16(Ld + (nb) + 16384 + (ks)*16384,        Bsrc + (t1)*128 + (ks)*64); \
    gload16(Ld + (nb) + 16384 + (ks)*16384 + 8192, Bsrc + (t1)*128 + (ks)*64 + 262144); } while(0)
#define LDA(buf, ks, m) (*(const bf16x8*)(ldsm + (buf) + (ks)*8192 + aBase + (m)*1024))
#define LDB(buf, ks, n) (*(const bf16x8*)(ldsm + (buf) + (ks)*16384 + bBase + (n)*1024))
#define VMCNT3() asm volatile("s_waitcnt vmcnt(3)" ::: "memory")
#define VMCNT0() asm volatile("s_waitcnt vmcnt(0)" ::: "memory")
#define BAR() __builtin_amdgcn_s_barrier()

    f32x4 acc[4][4];
#pragma unroll
    for (int i = 0; i < 4; ++i)
#pragma unroll
        for (int j = 0; j < 4; ++j)
#pragma unroll
            for (int r = 0; r < 4; ++r) acc[i][j][r] = 0.f;

    STG_A(0, 0, 0); STG_B(0, 0, 0); STG_A(1, 0, 0); STG_B(1, 0, 0);
    VMCNT3();
    BAR();

    bf16x8 af[2], bq[4];
#pragma unroll 1
    for (int t = 0; t < 15; ++t) {
        const int buf = (t & 1) * 49152;
        const int nb  = 49152 - buf;
        const int t1  = t + 1;
#pragma unroll
        for (int n = 0; n < 4; ++n) bq[n] = LDB(buf, 0, n);
        af[0] = LDA(buf, 0, 0); af[1] = LDA(buf, 0, 1);
        STG_A(0, nb, t1);
        BAR();
        __builtin_amdgcn_s_setprio(1);
#pragma unroll
        for (int m = 0; m < 2; ++m)
#pragma unroll
            for (int n = 0; n < 4; ++n)
                acc[m][n] = __builtin_amdgcn_mfma_f32_16x16x32_bf16(af[m], bq[n], acc[m][n], 0, 0, 0);
        __builtin_amdgcn_s_setprio(0);
        BAR();
        af[0] = LDA(buf, 0, 2); af[1] = LDA(buf, 0, 3);
        STG_B(0, nb, t1);
        VMCNT3();
        BAR();
        __builtin_amdgcn_s_setprio(1);
#pragma unroll
        for (int m = 0; m < 2; ++m)
#pragma unroll
            for (int n = 0; n < 4; ++n)
                acc[2 + m][n] = __builtin_amdgcn_mfma_f32_16x16x32_bf16(af[m], bq[n], acc[2 + m][n], 0, 0, 0);
        __builtin_amdgcn_s_setprio(0);
        BAR();
#pragma unroll
        for (int n = 0; n < 4; ++n) bq[n] = LDB(buf, 1, n);
        af[0] = LDA(buf, 1, 0); af[1] = LDA(buf, 1, 1);
        STG_A(1, nb, t1);
        BAR();
        __builtin_amdgcn_s_setprio(1);
#pragma unroll
        for (int m = 0; m < 2; ++m)
#pragma unroll
            for (int n = 0; n < 4; ++n)
                acc[m][n] = __builtin_amdgcn_mfma_f32_16x16x32_bf16(af[m], bq[n], acc[m][n], 0, 0, 0);
        __builtin_amdgcn_s_setprio(0);
        BAR();
        af[0] = LDA(buf, 1, 2); af[1] = LDA(buf, 1, 3);
        STG_B(1, nb, t1);
        VMCNT3();
        BAR();
        __builtin_amdgcn_s_setprio(1);
#pragma unroll
        for (int m = 0; m < 2; ++m)
#pragma unroll
            for (int n = 0; n < 4; ++n)
                acc[2 + m][n] = __builtin_amdgcn_mfma_f32_16x16x32_bf16(af[m], bq[n], acc[2 + m][n], 0, 0, 0);
        __builtin_amdgcn_s_setprio(0);
        BAR();
    }
    {   // peeled t = 15
        const int buf = 49152;
#pragma unroll
        for (int n = 0; n < 4; ++n) bq[n] = LDB(buf, 0, n);
        af[0] = LDA(buf, 0, 0); af[1] = LDA(buf, 0, 1);
#pragma unroll
        for (int m = 0; m < 2; ++m)
#pragma unroll
            for (int n = 0; n < 4; ++n)
                acc[m][n] = __builtin_amdgcn_mfma_f32_16x16x32_bf16(af[m], bq[n], acc[m][n], 0, 0, 0);
        af[0] = LDA(buf, 0, 2); af[1] = LDA(buf, 0, 3);
#pragma unroll
        for (int m = 0; m < 2; ++m)
#pragma unroll
            for (int n = 0; n < 4; ++n)
                acc[2 + m][n] = __builtin_amdgcn_mfma_f32_16x16x32_bf16(af[m], bq[n], acc[2 + m][n], 0, 0, 0);
        VMCNT0();
        BAR();
#pragma unroll
        for (int n = 0; n < 4; ++n) bq[n] = LDB(buf, 1, n);
        af[0] = LDA(buf, 1, 0); af[1] = LDA(buf, 1, 1);
#pragma unroll
        for (int m = 0; m < 2; ++m)
#pragma unroll
            for (int n = 0; n < 4; ++n)
                acc[m][n] = __builtin_amdgcn_mfma_f32_16x16x32_bf16(af[m], bq[n], acc[m][n], 0, 0, 0);
        af[0] = LDA(buf, 1, 2); af[1] = LDA(buf, 1, 3);
#pragma unroll
        for (int m = 0; m < 2; ++m)
#pragma unroll
            for (int n = 0; n < 4; ++n)
                acc[2 + m][n] = __builtin_amdgcn_mfma_f32_16x16x32_bf16(af[m], bq[n], acc[2 + m][n], 0, 0, 0);
    }
    const int er = lk << 2, ec = lm;
#pragma unroll
    for (int m = 0; m < 4; ++m) {
        int row = m0 + wr * 64 + m * 16 + er;
#pragma unroll
        for (int n = 0; n < 4; ++n) {
            int col = n0 + wc * 64 + n * 16 + ec;
            ushort* cp = C + (size_t)row * ldc + col;
#pragma unroll
            for (int r = 0; r < 4; ++r)
                cp[(size_t)r * ldc] = f2bf(acc[m][n][r] + bias[row + r]);
        }
    }
#undef STG_A
#undef STG_B
#undef LDA
#undef LDB
#undef VMCNT3
#undef VMCNT0
#undef BAR
}

// ---------------------------------------------------------------------------
// 128x128 m97-structure MFMA GEMM (out-projection, bias per col, writes f32)
// ---------------------------------------------------------------------------
__global__ __launch_bounds__(256) void k_gemm_bf16(
    const ushort* __restrict__ A, const ushort* __restrict__ B,
    const float* __restrict__ bias, float* __restrict__ C, int ldc)
{
    __shared__ ushort As[128 * 32];
    __shared__ ushort Bs[128 * 32];
    const int tid  = threadIdx.x;
    const int lane = tid & 63;
    const int w    = tid >> 6;
    const int wm   = (w >> 1) << 6, wn = (w & 1) << 6;
    const int m0   = blockIdx.y << 7, n0 = blockIdx.x << 7;

    f32x4 acc[4][4];
#pragma unroll
    for (int i = 0; i < 4; ++i)
#pragma unroll
        for (int j = 0; j < 4; ++j)
#pragma unroll
            for (int r = 0; r < 4; ++r) acc[i][j][r] = 0.f;

    const char* Ab = (const char*)A + ((size_t)(m0 + (tid >> 2)) << 11) + ((tid & 3) << 4);
    const char* Bb = (const char*)B + ((size_t)(n0 + (tid >> 2)) << 11) + ((tid & 3) << 4);
    char* AsD = (char*)As + tid * 16;
    char* BsD = (char*)Bs + tid * 16;
    const char* ap = (const char*)As + ((wm + (lane & 15)) << 6) + ((lane >> 4) << 4);
    const char* bp = (const char*)Bs + ((wn + (lane & 15)) << 6) + ((lane >> 4) << 4);

    for (int k0 = 0; k0 < 1024; k0 += 32) {
        __syncthreads();
        gload16(AsD,        Ab + k0 * 2);
        gload16(AsD + 4096, Ab + 131072 + k0 * 2);
        gload16(BsD,        Bb + k0 * 2);
        gload16(BsD + 4096, Bb + 131072 + k0 * 2);
        __syncthreads();
        bf16x8 af[4], bfr[4];
#pragma unroll
        for (int i = 0; i < 4; ++i) {
            af[i]  = *(const bf16x8*)(ap + (i << 10));
            bfr[i] = *(const bf16x8*)(bp + (i << 10));
        }
#pragma unroll
        for (int i = 0; i < 4; ++i)
#pragma unroll
            for (int j = 0; j < 4; ++j)
                acc[i][j] = __builtin_amdgcn_mfma_f32_16x16x32_bf16(
                    af[i], bfr[j], acc[i][j], 0, 0, 0);
    }
    const int er = (lane >> 4) << 2;
    const int ec = lane & 15;
#pragma unroll
    for (int i = 0; i < 4; ++i) {
        int row = m0 + wm + (i << 4) + er;
#pragma unroll
        for (int j = 0; j < 4; ++j) {
            int col = n0 + wn + (j << 4) + ec;
            float bz = bias[col];
            float* cp = C + (size_t)row * ldc + col;
#pragma unroll
            for (int r = 0; r < 4; ++r)
                cp[(size_t)r * ldc] = acc[i][j][r] + bz;
        }
    }
}

// ---------------------------------------------------------------------------
// K3a: filter MLP (256 blocks x 16 t)
// ---------------------------------------------------------------------------
__global__ __launch_bounds__(256) void k_filt_mlp(
    const float* __restrict__ z, const float* __restrict__ w0,
    const float* __restrict__ b0, const float* __restrict__ fr,
    const float* __restrict__ w1, const float* __restrict__ b1,
    const float* __restrict__ w2, const float* __restrict__ b2,
    float* __restrict__ H3)
{
    __shared__ float w1t[64 * 65];
    __shared__ float w2t[64 * 65];
    __shared__ float hb[4][64];
    const int tid = threadIdx.x;
    for (int idx = tid; idx < 4096; idx += 256) {
        int j = idx >> 6, m = idx & 63;
        w1t[m*65 + j] = w1[idx];
        w2t[m*65 + j] = w2[idx];
    }
    __syncthreads();
    const int tl = tid >> 6, j = tid & 63;
    const float frj = fr[j];
    const float b0j = b0[j], b1j = b1[j], b2j = b2[j];
    const float w00 = w0[j*3+0], w01 = w0[j*3+1], w02 = w0[j*3+2];
    const int t0 = blockIdx.x * 16;
    for (int r = 0; r < 4; ++r) {
        int t = t0 + r*4 + tl;
        float z0 = z[t*3+0], z1 = z[t*3+1], z2 = z[t*3+2];
        float h = sinf(frj * (b0j + z0*w00 + z1*w01 + z2*w02));
        hb[tl][j] = h;
        __syncthreads();
        float s = b1j;
#pragma unroll
        for (int m = 0; m < 64; ++m) s = fmaf(hb[tl][m], w1t[m*65 + j], s);
        __syncthreads();
        h = sinf(frj * s);
        hb[tl][j] = h;
        __syncthreads();
        s = b2j;
#pragma unroll
        for (int m = 0; m < 64; ++m) s = fmaf(hb[tl][m], w2t[m*65 + j], s);
        h = sinf(frj * s);
        H3[(size_t)t * 64 + j] = h;
        __syncthreads();
    }
}

// ---------------------------------------------------------------------------
// K3b: kf[d][t] = (H3 @ wf^T) * exp-decay
// ---------------------------------------------------------------------------
__global__ __launch_bounds__(256) void k_filt_k(
    const float* __restrict__ H3, const float* __restrict__ wf,
    float* __restrict__ kf)
{
    __shared__ float Hs[64][65];
    __shared__ float Ws[64][65];
    const int tid = threadIdx.x;
    const int t0 = blockIdx.x * 64, d0 = blockIdx.y * 64;
    for (int idx = tid; idx < 4096; idx += 256) {
        int r = idx >> 6, cc = idx & 63;
        Hs[r][cc] = H3[(size_t)(t0 + r) * 64 + cc];
        Ws[r][cc] = wf[(size_t)(d0 + r) * 64 + cc];
    }
    __syncthreads();
    const int tx = tid & 15, ty = tid >> 4;
    float acc[4][4];
#pragma unroll
    for (int i = 0; i < 4; ++i)
#pragma unroll
        for (int jj = 0; jj < 4; ++jj) acc[i][jj] = 0.f;
#pragma unroll
    for (int j = 0; j < 64; ++j) {
        float wv[4], hv[4];
#pragma unroll
        for (int i = 0; i < 4; ++i) wv[i] = Ws[4*ty + i][j];
#pragma unroll
        for (int i = 0; i < 4; ++i) hv[i] = Hs[4*tx + i][j];
#pragma unroll
        for (int i = 0; i < 4; ++i)
#pragma unroll
            for (int jj = 0; jj < 4; ++jj) acc[i][jj] = fmaf(wv[i], hv[jj], acc[i][jj]);
    }
    const float mind = -3.0701134573253944f;
    const float maxd = -15.350567286626972f;
#pragma unroll
    for (int i = 0; i < 4; ++i) {
        int d = d0 + 4*ty + i;
        float delta = fabsf(mind + (maxd - mind) * ((float)d / 1023.f));
#pragma unroll
        for (int jj = 0; jj < 4; ++jj) {
            int t = t0 + 4*tx + jj;
            float tn = (float)t / 4095.f;
            kf[(size_t)d * LL + t] = acc[i][jj] * expf(-tn * delta);
        }
    }
}

// ---------------------------------------------------------------------------
// FFT helpers (8192-pt). LDS part: 3 radix-8 passes (fwd: h=2048,256,32;
// inv mirrored), each = exact composition of three radix-2 DIF/DIT stages.
// Register part: 2x 8-point (h=4,2,1). Load fuses radix-2 h=4096; epilogue
// fuses inverse h=4096. One sincos per thread per pass (q shared by both
// octets since 512 % hh == 0 for hh in {512,64,8}).
// ---------------------------------------------------------------------------
__device__ __forceinline__ int pidx(int p) { return p + (p >> 4); }

__device__ __forceinline__ float2 cmul(float2 a, float2 b) {
    return make_float2(a.x*b.x - a.y*b.y, a.x*b.y + a.y*b.x);
}
__device__ __forceinline__ float2 cadd(float2 a, float2 b) {
    return make_float2(a.x + b.x, a.y + b.y);
}
__device__ __forceinline__ float2 csub(float2 a, float2 b) {
    return make_float2(a.x - b.x, a.y - b.y);
}
__device__ __forceinline__ float2 cmulni(float2 a) {  // * (-i)
    return make_float2(a.y, -a.x);
}
__device__ __forceinline__ float2 cmulpi(float2 a) {  // * (+i)
    return make_float2(-a.y, a.x);
}

// forward radix-8 pass: composes radix-2 DIF stages h, h/2, h/4
__device__ __forceinline__ void r8f_pass(float2* buf, int tid, int h, int lh) {
    const int hh = h >> 2;
    const float rinv = -FPI / (float)h;
    const int q = tid & (hh - 1);
    float sn, cs;
    __sincosf(rinv * (float)q, &sn, &cs);
    float2 w  = make_float2(cs, sn);                         // omega
    float2 wc = make_float2((cs + sn)*RCQ, (sn - cs)*RCQ);   // omega * e^{-i pi/4}
    float2 w2 = cmul(w, w);
    float2 w4 = cmul(w2, w2);
    __syncthreads();
#pragma unroll
    for (int r = 0; r < 2; ++r) {
        int bf = tid + (r << 9);
        int g  = bf >> lh;
        int j  = (g << (lh + 3)) + q;
        float2 x0 = buf[pidx(j)];
        float2 x1 = buf[pidx(j + hh)];
        float2 x2 = buf[pidx(j + 2*hh)];
        float2 x3 = buf[pidx(j + 3*hh)];
        float2 x4 = buf[pidx(j + 4*hh)];
        float2 x5 = buf[pidx(j + 5*hh)];
        float2 x6 = buf[pidx(j + 6*hh)];
        float2 x7 = buf[pidx(j + 7*hh)];
        // stage 1 (dist 4*hh = h)
        float2 u0 = cadd(x0, x4), u1 = cadd(x1, x5);
        float2 u2 = cadd(x2, x6), u3 = cadd(x3, x7);
        float2 v0 = cmul(csub(x0, x4), w);
        float2 v1 = cmul(csub(x1, x5), wc);
        float2 v2 = cmulni(cmul(csub(x2, x6), w));
        float2 v3 = cmulni(cmul(csub(x3, x7), wc));
        // stage 2 (dist 2*hh)
        float2 A0 = cadd(u0, u2), A1 = cadd(u1, u3);
        float2 B0 = cmul(csub(u0, u2), w2);
        float2 B1 = cmulni(cmul(csub(u1, u3), w2));
        float2 C0 = cadd(v0, v2), C1 = cadd(v1, v3);
        float2 D0 = cmul(csub(v0, v2), w2);
        float2 D1 = cmulni(cmul(csub(v1, v3), w2));
        // stage 3 (dist hh), twiddle w4
        buf[pidx(j)]        = cadd(A0, A1);
        buf[pidx(j + hh)]   = cmul(csub(A0, A1), w4);
        buf[pidx(j + 2*hh)] = cadd(B0, B1);
        buf[pidx(j + 3*hh)] = cmul(csub(B0, B1), w4);
        buf[pidx(j + 4*hh)] = cadd(C0, C1);
        buf[pidx(j + 5*hh)] = cmul(csub(C0, C1), w4);
        buf[pidx(j + 6*hh)] = cadd(D0, D1);
        buf[pidx(j + 7*hh)] = cmul(csub(D0, D1), w4);
    }
}

// inverse radix-8 pass: exact mirror (conjugated twiddles, reversed stages)
__device__ __forceinline__ void r8i_pass(float2* buf, int tid, int h, int lh) {
    const int hh = h >> 2;
    const float rpos = FPI / (float)h;
    const int q = tid & (hh - 1);
    float sn, cs;
    __sincosf(rpos * (float)q, &sn, &cs);
    float2 w  = make_float2(cs, sn);                         // conj(omega)
    float2 wc = make_float2((cs - sn)*RCQ, (sn + cs)*RCQ);   // w * e^{+i pi/4}
    float2 w2 = cmul(w, w);
    float2 w4 = cmul(w2, w2);
    __syncthreads();
#pragma unroll
    for (int r = 0; r < 2; ++r) {
        int bf = tid + (r << 9);
        int g  = bf >> lh;
        int j  = (g << (lh + 3)) + q;
        float2 y0 = buf[pidx(j)];
        float2 y1 = buf[pidx(j + hh)];
        float2 y2 = buf[pidx(j + 2*hh)];
        float2 y3 = buf[pidx(j + 3*hh)];
        float2 y4 = buf[pidx(j + 4*hh)];
        float2 y5 = buf[pidx(j + 5*hh)];
        float2 y6 = buf[pidx(j + 6*hh)];
        float2 y7 = buf[pidx(j + 7*hh)];
        // undo stage 3
        float2 s;
        s = cmul(y1, w4); float2 A0 = cadd(y0, s), A1 = csub(y0, s);
        s = cmul(y3, w4); float2 B0 = cadd(y2, s), B1 = csub(y2, s);
        s = cmul(y5, w4); float2 C0 = cadd(y4, s), C1 = csub(y4, s);
        s = cmul(y7, w4); float2 D0 = cadd(y6, s), D1 = csub(y6, s);
        // undo stage 2
        s = cmul(B0, w2);          float2 u0 = cadd(A0, s), u2 = csub(A0, s);
        s = cmulpi(cmul(B1, w2));  float2 u1 = cadd(A1, s), u3 = csub(A1, s);
        s = cmul(D0, w2);          float2 v0 = cadd(C0, s), v2 = csub(C0, s);
        s = cmulpi(cmul(D1, w2));  float2 v1 = cadd(C1, s), v3 = csub(C1, s);
        // undo stage 1
        s = cmul(v0, w);           buf[pidx(j)]        = cadd(u0, s);
                                   buf[pidx(j + 4*hh)] = csub(u0, s);
        s = cmul(v1, wc);          buf[pidx(j + hh)]   = cadd(u1, s);
                                   buf[pidx(j + 5*hh)] = csub(u1, s);
        s = cmulpi(cmul(v2, w));   buf[pidx(j + 2*hh)] = cadd(u2, s);
                                   buf[pidx(j + 6*hh)] = csub(u2, s);
        s = cmulpi(cmul(v3, wc));  buf[pidx(j + 3*hh)] = cadd(u3, s);
                                   buf[pidx(j + 7*hh)] = csub(u3, s);
    }
}

__device__ void fft_lds_fwd8(float2* buf, int tid) {
    r8f_pass(buf, tid, 2048, 9);
    r8f_pass(buf, tid, 256, 6);
    r8f_pass(buf, tid, 32, 3);
    __syncthreads();
}

__device__ void fft_lds_inv8(float2* buf, int tid) {
    r8i_pass(buf, tid, 32, 3);
    r8i_pass(buf, tid, 256, 6);
    r8i_pass(buf, tid, 2048, 9);
    __syncthreads();
}

// register FFT: two independent 8-point halves (h=4,2,1)
__device__ __forceinline__ void fft_reg_fwd(float2* c) {
    const float W8r[4] = {1.f, 0.70710678f, 0.f, -0.70710678f};
    const float W8i[4] = {0.f, -0.70710678f, -1.f, -0.70710678f};
#pragma unroll
    for (int blk = 0; blk < 16; blk += 8)
#pragma unroll
        for (int k = 0; k < 4; ++k) {
            float2 a = c[blk+k], b = c[blk+k+4];
            float2 d = csub(a, b);
            c[blk+k]   = cadd(a, b);
            c[blk+k+4] = cmul(d, make_float2(W8r[k], W8i[k]));
        }
#pragma unroll
    for (int blk = 0; blk < 16; blk += 4) {
        {   float2 a = c[blk], b = c[blk+2];
            c[blk]   = cadd(a, b);
            c[blk+2] = csub(a, b); }
        {   float2 a = c[blk+1], b = c[blk+3];
            float2 d = csub(a, b);
            c[blk+1] = cadd(a, b);
            c[blk+3] = make_float2(d.y, -d.x); }
    }
#pragma unroll
    for (int blk = 0; blk < 16; blk += 2) {
        float2 a = c[blk], b = c[blk+1];
        c[blk]   = cadd(a, b);
        c[blk+1] = csub(a, b);
    }
}

__device__ __forceinline__ void fft_reg_inv(float2* c) {
#pragma unroll
    for (int blk = 0; blk < 16; blk += 2) {
        float2 a = c[blk], b = c[blk+1];
        c[blk]   = cadd(a, b);
        c[blk+1] = csub(a, b);
    }
#pragma unroll
    for (int blk = 0; blk < 16; blk += 4) {
        {   float2 a = c[blk], b = c[blk+2];
            c[blk]   = cadd(a, b);
            c[blk+2] = csub(a, b); }
        {   float2 a = c[blk+1], b = c[blk+3];
            float2 bt = make_float2(-c[blk+3].y, c[blk+3].x);
            c[blk+1] = cadd(a, bt);
            c[blk+3] = csub(a, bt); }
    }
    const float W8r[4] = {1.f, 0.70710678f, 0.f, -0.70710678f};
    const float W8i[4] = {0.f, 0.70710678f, 1.f, 0.70710678f};
#pragma unroll
    for (int blk = 0; blk < 16; blk += 8)
#pragma unroll
        for (int k = 0; k < 4; ++k) {
            float2 a = c[blk+k], b = c[blk+k+4];
            float2 bt = cmul(b, make_float2(W8r[k], W8i[k]));
            c[blk+k]   = cadd(a, bt);
            c[blk+k+4] = csub(a, bt);
        }
}

// ---------------------------------------------------------------------------
// K4a: kernel spectrum -> fp16x2 (scrambled, pre-scaled by 1/8192)
// ---------------------------------------------------------------------------
__global__ __launch_bounds__(512) void k_kfft(
    const float* __restrict__ kf, f16x2* __restrict__ Kf)
{
    __shared__ float2 buf[8704];
    const int d = blockIdx.x, tid = threadIdx.x;
    const float* krow = kf + (size_t)d * LL;
    const float rinv0 = -FPI / 4096.f;
    for (int i = tid; i < 1024; i += 512) {
        float4 k4 = reinterpret_cast<const float4*>(krow)[i];
        int p = 4 * i;
        float kv[4] = {k4.x, k4.y, k4.z, k4.w};
#pragma unroll
        for (int q = 0; q < 4; ++q) {
            float sn, cs;
            __sincosf(rinv0 * (float)(p + q), &sn, &cs);
            buf[pidx(p + q)]        = make_float2(kv[q], 0.f);
            buf[pidx(p + q + 4096)] = make_float2(kv[q] * cs, kv[q] * sn);
        }
    }
    fft_lds_fwd8(buf, tid);
    float2 c[16];
    const int p0 = tid * 16;
#pragma unroll
    for (int j = 0; j < 16; ++j) c[j] = buf[pidx(p0 + j)];
    fft_reg_fwd(c);
    f16x2* outp = Kf + (size_t)d * 8192 + p0;
#pragma unroll
    for (int j = 0; j < 16; ++j) {
        f16x2 o;
        o[0] = (_Float16)(c[j].x * (1.f/8192.f));
        o[1] = (_Float16)(c[j].y * (1.f/8192.f));
        outp[j] = o;
    }
}

// ---------------------------------------------------------------------------
// conv4: causal 3-tap depthwise conv on a bf16 row, 4 outputs at p..p+3
// ---------------------------------------------------------------------------
__device__ __forceinline__ void conv4(const ushort* __restrict__ row, int p,
    float w0, float w1, float w2, float bias, float* out)
{
    float xm2, xm1;
    if (p >= 2) {
        unsigned prev = *reinterpret_cast<const unsigned*>(row + p - 2);
        xm2 = bf2f((ushort)(prev & 0xffffu));
        xm1 = bf2f((ushort)(prev >> 16));
    } else { xm2 = 0.f; xm1 = 0.f; }
    uint2 cur = *reinterpret_cast<const uint2*>(row + p);
    float x0 = bf2f((ushort)(cur.x & 0xffffu));
    float x1 = bf2f((ushort)(cur.x >> 16));
    float x2 = bf2f((ushort)(cur.y & 0xffffu));
    float x3 = bf2f((ushort)(cur.y >> 16));
    out[0] = fmaf(w2, x0, fmaf(w1, xm1, fmaf(w0, xm2, bias)));
    out[1] = fmaf(w2, x1, fmaf(w1, x0,  fmaf(w0, xm1, bias)));
    out[2] = fmaf(w2, x2, fmaf(w1, x1,  fmaf(w0, x0,  bias)));
    out[3] = fmaf(w2, x3, fmaf(w1, x2,  fmaf(w0, x1,  bias)));
}

// ---------------------------------------------------------------------------
// K4b: per channel d, 3-tap conv of v,x1 from channel-major up2 (bf16),
// gate vin = v*x1, batch-folded FFT conv (z = vin0 + i*vin1) against f16
// spectrum Kf, D*vin skip (vin kept in registers), x0-conv gate, bf16 out.
// ---------------------------------------------------------------------------
__global__ __launch_bounds__(512) void k_fftconv(
    const ushort* __restrict__ up2, const f16x2* __restrict__ Kf,
    const float* __restrict__ sfw, const float* __restrict__ sfb,
    const float* __restrict__ Dp, ushort* __restrict__ yg)
{
    __shared__ float2 buf[8704];
    const int d = blockIdx.x, tid = threadIdx.x;
    const ushort* vrow0  = up2 + (size_t)(2048 + d) * 8192;
    const ushort* vrow1  = vrow0 + 4096;
    const ushort* x1row0 = up2 + (size_t)(1024 + d) * 8192;
    const ushort* x1row1 = x1row0 + 4096;
    const ushort* x0row0 = up2 + (size_t)d * 8192;
    const ushort* x0row1 = x0row0 + 4096;
    const float wv0 = sfw[(2048+d)*3+0], wv1 = sfw[(2048+d)*3+1],
                wv2 = sfw[(2048+d)*3+2], bv = sfb[2048+d];
    const float wx0 = sfw[(1024+d)*3+0], wx1 = sfw[(1024+d)*3+1],
                wx2 = sfw[(1024+d)*3+2], bx = sfb[1024+d];
    const float g0 = sfw[d*3+0], g1 = sfw[d*3+1], g2 = sfw[d*3+2], bg = sfb[d];
    const float rinv0 = -FPI / 4096.f;

    float vs0[8], vs1[8];     // gated conv values, kept live for the D-skip
#pragma unroll
    for (int ii = 0; ii < 2; ++ii) {
        int p = 4 * tid + ii * 2048;
        float cv0[4], cv1[4], cx0[4], cx1[4];
        conv4(vrow0,  p, wv0, wv1, wv2, bv, cv0);
        conv4(vrow1,  p, wv0, wv1, wv2, bv, cv1);
        conv4(x1row0, p, wx0, wx1, wx2, bx, cx0);
        conv4(x1row1, p, wx0, wx1, wx2, bx, cx1);
#pragma unroll
        for (int q = 0; q < 4; ++q) {
            float z0 = cv0[q] * cx0[q];
            float z1 = cv1[q] * cx1[q];
            vs0[ii*4 + q] = z0;
            vs1[ii*4 + q] = z1;
            float sn, cs;
            __sincosf(rinv0 * (float)(p + q), &sn, &cs);
            float2 z = make_float2(z0, z1);
            buf[pidx(p + q)]        = z;
            buf[pidx(p + q + 4096)] = cmul(z, make_float2(cs, sn));
        }
    }
    fft_lds_fwd8(buf, tid);
    float2 c[16];
    const int p0 = tid * 16;
#pragma unroll
    for (int j = 0; j < 16; ++j) c[j] = buf[pidx(p0 + j)];
    fft_reg_fwd(c);
    const f16x2* kfr = Kf + (size_t)d * 8192 + p0;
#pragma unroll
    for (int j = 0; j < 16; ++j) {
        f16x2 kv = kfr[j];
        c[j] = cmul(c[j], make_float2((float)kv[0], (float)kv[1]));
    }
    fft_reg_inv(c);
#pragma unroll
    for (int j = 0; j < 16; ++j) buf[pidx(p0 + j)] = c[j];
    fft_lds_inv8(buf, tid);
    const float Dd = Dp[d];
    ushort* orow0 = yg + (size_t)d * LL;
    ushort* orow1 = yg + ((size_t)DM + d) * LL;
    const float rinv4 = FPI / 4096.f;
#pragma unroll
    for (int ii = 0; ii < 2; ++ii) {
        int p = 4 * tid + ii * 2048;
        float cg0[4], cg1[4];
        conv4(x0row0, p, g0, g1, g2, bg, cg0);
        conv4(x0row1, p, g0, g1, g2, bg, cg1);
        ushort s0[4], s1[4];
#pragma unroll
        for (int q = 0; q < 4; ++q) {
            float sn, cs;
            __sincosf(rinv4 * (float)(p + q), &sn, &cs);
            float2 a  = buf[pidx(p + q)];
            float2 bb = buf[pidx(p + q + 4096)];
            float2 bt = cmul(bb, make_float2(cs, sn));
            s0[q] = f2bf((a.x + bt.x + Dd * vs0[ii*4 + q]) * cg0[q]);
            s1[q] = f2bf((a.y + bt.y + Dd * vs1[ii*4 + q]) * cg1[q]);
        }
        *reinterpret_cast<ushort4*>(orow0 + p) = make_ushort4(s0[0], s0[1], s0[2], s0[3]);
        *reinterpret_cast<ushort4*>(orow1 + p) = make_ushort4(s1[0], s1[1], s1[2], s1[3]);
    }
}

// ---------------------------------------------------------------------------
// K_tr: yg[b][d][t] (bf16) -> Ag[b][t][d] (bf16), 64x64 LDS tiles
// ---------------------------------------------------------------------------
__global__ __launch_bounds__(256) void k_tr(
    const ushort* __restrict__ yg, ushort* __restrict__ Ag)
{
    __shared__ ushort S[64][72];
    const int b  = blockIdx.z;
    const int d0 = blockIdx.y * 64;
    const int t0 = blockIdx.x * 64;
    const int tid = threadIdx.x;
#pragma unroll
    for (int p = 0; p < 2; ++p) {
        int idx = p * 256 + tid;
        int dr = idx >> 3, c8 = (idx & 7) << 3;
        uint4 v = *reinterpret_cast<const uint4*>(
            yg + ((size_t)b * DM + d0 + dr) * LL + t0 + c8);
        *reinterpret_cast<uint4*>(&S[dr][c8]) = v;
    }
    __syncthreads();
#pragma unroll
    for (int p = 0; p < 2; ++p) {
        int idx = p * 256 + tid;
        int tr = idx >> 3, dq = (idx & 7) << 3;
        ushort tmp[8] __attribute__((aligned(16)));
#pragma unroll
        for (int q = 0; q < 8; ++q) tmp[q] = S[dq + q][tr];
        *reinterpret_cast<uint4*>(Ag + ((size_t)b * LL + t0 + tr) * DM + d0 + dq) =
            *reinterpret_cast<uint4*>(tmp);
    }
}

// ---------------------------------------------------------------------------
extern "C" void kernel_launch(void* const* d_in, const int* in_sizes, int n_in,
                              void* d_out, int out_size, void* d_ws, size_t ws_size,
                              hipStream_t stream)
{
    if (n_in < 17) return;
    const float* u    = (const float*)d_in[0];
    const float* w_in = (const float*)d_in[1];
    const float* b_in = (const float*)d_in[2];
    const float* sf_w = (const float*)d_in[3];
    const float* sf_b = (const float*)d_in[4];
    const float* z    = (const float*)d_in[5];
    const float* w0   = (const float*)d_in[6];
    const float* b0   = (const float*)d_in[7];
    const float* freq = (const float*)d_in[8];
    const float* w1   = (const float*)d_in[9];
    const float* b1   = (const float*)d_in[10];
    const float* w2   = (const float*)d_in[11];
    const float* b2   = (const float*)d_in[12];
    const float* wf   = (const float*)d_in[13];
    const float* Dp   = (const float*)d_in[14];
    const float* wout = (const float*)d_in[15];
    const float* bout = (const float*)d_in[16];
    float* out = (float*)d_out;
    float* ws  = (float*)d_ws;

    // Overlaid workspace (float offsets):
    //  [0, 12582912)           up2 bf16 [3072][8192] (P2-P6)
    //  [16777216, +4194304)    kf f32 (P4-P5) -> yg bf16 (P6-P7)
    //  [20971520, +4194304)    H3 f32 (P3-P4) -> Ag bf16 (P7-P8)
    //  [25165824, +4194304)    ub bf16 (P1-P2)
    //  [33554432, +8388608)    wb bf16 (P1-P2) -> Kf f16x2 (P5-P6)
    //  [41943040, +524288)     woutb bf16 (P1-P8)
    ushort* up2   = (ushort*)ws;
    float*  kfbuf = ws + 16777216;
    ushort* yg    = (ushort*)(ws + 16777216);
    float*  H3    = ws + 20971520;
    ushort* Ag    = (ushort*)(ws + 20971520);
    ushort* ub    = (ushort*)(ws + 25165824);
    ushort* wb    = (ushort*)(ws + 33554432);
    f16x2*  Kf    = (f16x2*)(ws + 33554432);
    ushort* woutb = (ushort*)(ws + 41943040);
    const size_t NEED = (size_t)(41943040 + 524288) * 4;
    if (ws_size < NEED) return;

    hipLaunchKernelGGL(k_cvt3,     dim3(2048), dim3(256), 0, stream,
                       u, ub, 2097152, w_in, wb, 786432, wout, woutb, 262144);
    hipLaunchKernelGGL(k_gemm128n, dim3((E3/128) * (8192/256)), dim3(512), 0, stream,
                       wb, ub, b_in, up2, 8192/256, 8192);
    hipLaunchKernelGGL(k_filt_mlp, dim3(LL/16), dim3(256), 0, stream,
                       z, w0, b0, freq, w1, b1, w2, b2, H3);
    hipLaunchKernelGGL(k_filt_k,   dim3(LL/64, DM/64), dim3(256), 0, stream,
                       H3, wf, kfbuf);
    hipLaunchKernelGGL(k_kfft,     dim3(DM), dim3(512), 0, stream,
                       kfbuf, Kf);
    hipLaunchKernelGGL(k_fftconv,  dim3(DM), dim3(512), 0, stream,
                       up2, Kf, sf_w, sf_b, Dp, yg);
    hipLaunchKernelGGL(k_tr,       dim3(LL/64, DM/64, NB), dim3(256), 0, stream,
                       yg, Ag);
    hipLaunchKernelGGL(k_gemm_bf16, dim3(DM/128, 8192/128), dim3(256), 0, stream,
                       Ag, woutb, bout, out, DM);
}

// Round 14
// 218.915 us; speedup vs baseline: 1.1303x; 1.1303x over previous
//
#include <hip/hip_runtime.h>
#include <math.h>

#define DM   1024
#define LL   4096
#define NB   2
#define E3   3072
#define FPI  3.14159265358979323846f

typedef __bf16 bf16x8 __attribute__((ext_vector_type(8)));
typedef float  f32x4  __attribute__((ext_vector_type(4)));
typedef _Float16 f16x2 __attribute__((ext_vector_type(2)));

__device__ __forceinline__ unsigned short f2bf(float x) {
    unsigned u = __float_as_uint(x);
    u += 0x7fffu + ((u >> 16) & 1u);
    return (unsigned short)(u >> 16);
}
__device__ __forceinline__ float bf2f(ushort s) {
    return __uint_as_float(((unsigned)s) << 16);
}
__device__ __forceinline__ void gload16(void* lds, const void* g) {
    typedef const __attribute__((address_space(1))) unsigned int* gp_t;
    typedef __attribute__((address_space(3))) unsigned int* lp_t;
    __builtin_amdgcn_global_load_lds((gp_t)g, (lp_t)lds, 16, 0, 0);
}

// ---------------------------------------------------------------------------
// cvt3: f32 -> bf16 for three arrays in one launch
// ---------------------------------------------------------------------------
__global__ __launch_bounds__(256) void k_cvt3(
    const float* __restrict__ a, ushort* __restrict__ oa, int n4a,
    const float* __restrict__ b, ushort* __restrict__ ob, int n4b,
    const float* __restrict__ c, ushort* __restrict__ oc, int n4c)
{
    int idx = blockIdx.x * 256 + threadIdx.x;
    int stride = gridDim.x * 256;
    int tot = n4a + n4b + n4c;
    for (int i = idx; i < tot; i += stride) {
        const float4* src; ushort* dst; int k;
        if (i < n4a)            { src = (const float4*)a; dst = oa; k = i; }
        else if (i < n4a + n4b) { src = (const float4*)b; dst = ob; k = i - n4a; }
        else                    { src = (const float4*)c; dst = oc; k = i - n4a - n4b; }
        float4 v = src[k];
        ushort4 o;
        o.x = f2bf(v.x); o.y = f2bf(v.y); o.z = f2bf(v.z); o.w = f2bf(v.w);
        *reinterpret_cast<ushort4*>(dst + 4 * k) = o;
    }
}

// ---------------------------------------------------------------------------
// 128x256 4-phase bf16 MFMA GEMM (K=1024), bias PER ROW, writes bf16.
// Up-projection in SWAPPED form: C[e][m] = W[e,:]·u[m,:] + b[e].
// XCD swizzle: each XCD owns a contiguous chunk of Ntiles/8 n-tiles.
// ---------------------------------------------------------------------------
__global__ __launch_bounds__(512, 1) void k_gemm128n(
    const ushort* __restrict__ A, const ushort* __restrict__ B,
    const float* __restrict__ bias, ushort* __restrict__ C,
    int Ntiles, int ldc)
{
    __shared__ __align__(16) char ldsm[98304];
    const int tid  = threadIdx.x;
    const int lane = tid & 63;
    const int w    = tid >> 6;
    const int wr   = w >> 2, wc = w & 3;

    const int nch = Ntiles >> 3;
    const int xcd = blockIdx.x & 7;
    const int loc = blockIdx.x >> 3;
    const int n0 = ((xcd * nch) + (loc % nch)) << 8;
    const int m0 = (loc / nch) << 7;

    const int r0 = tid >> 2;
    const int swzc = ((tid & 3) ^ ((r0 >> 1) & 3)) << 4;
    const char* Asrc = (const char*)A + ((size_t)(m0 + r0) << 11) + swzc;
    const char* Bsrc = (const char*)B + ((size_t)(n0 + r0) << 11) + swzc;
    char* Ld = ldsm + tid * 16;

    const int lm = lane & 15, lk = lane >> 4;
    const int rA = wr * 64 + lm;
    const int rB = wc * 64 + lm;
    const int aBase = rA * 64 + ((lk ^ ((rA >> 1) & 3)) << 4);
    const int bBase = 16384 + rB * 64 + ((lk ^ ((rB >> 1) & 3)) << 4);

#define STG_A(ks, nb, t1) \
    gload16(Ld + (nb) + (ks)*8192, Asrc + (t1)*128 + (ks)*64)
#define STG_B(ks, nb, t1) do { \
    gload16(Ld + (nb) + 16384 + (ks)*16384,        Bsrc + (t1)*128 + (ks)*64); \
    gload16(Ld + (nb) + 16384 + (ks)*16384 + 8192, Bsrc + (t1)*128 + (ks)*64 + 262144); } while(0)
#define LDA(buf, ks, m) (*(const bf16x8*)(ldsm + (buf) + (ks)*8192 + aBase + (m)*1024))
#define LDB(buf, ks, n) (*(const bf16x8*)(ldsm + (buf) + (ks)*16384 + bBase + (n)*1024))
#define VMCNT3() asm volatile("s_waitcnt vmcnt(3)" ::: "memory")
#define VMCNT0() asm volatile("s_waitcnt vmcnt(0)" ::: "memory")
#define BAR() __builtin_amdgcn_s_barrier()

    f32x4 acc[4][4];
#pragma unroll
    for (int i = 0; i < 4; ++i)
#pragma unroll
        for (int j = 0; j < 4; ++j)
#pragma unroll
            for (int r = 0; r < 4; ++r) acc[i][j][r] = 0.f;

    STG_A(0, 0, 0); STG_B(0, 0, 0); STG_A(1, 0, 0); STG_B(1, 0, 0);
    VMCNT3();
    BAR();

    bf16x8 af[2], bq[4];
#pragma unroll 1
    for (int t = 0; t < 15; ++t) {
        const int buf = (t & 1) * 49152;
        const int nb  = 49152 - buf;
        const int t1  = t + 1;
#pragma unroll
        for (int n = 0; n < 4; ++n) bq[n] = LDB(buf, 0, n);
        af[0] = LDA(buf, 0, 0); af[1] = LDA(buf, 0, 1);
        STG_A(0, nb, t1);
        BAR();
        __builtin_amdgcn_s_setprio(1);
#pragma unroll
        for (int m = 0; m < 2; ++m)
#pragma unroll
            for (int n = 0; n < 4; ++n)
                acc[m][n] = __builtin_amdgcn_mfma_f32_16x16x32_bf16(af[m], bq[n], acc[m][n], 0, 0, 0);
        __builtin_amdgcn_s_setprio(0);
        BAR();
        af[0] = LDA(buf, 0, 2); af[1] = LDA(buf, 0, 3);
        STG_B(0, nb, t1);
        VMCNT3();
        BAR();
        __builtin_amdgcn_s_setprio(1);
#pragma unroll
        for (int m = 0; m < 2; ++m)
#pragma unroll
            for (int n = 0; n < 4; ++n)
                acc[2 + m][n] = __builtin_amdgcn_mfma_f32_16x16x32_bf16(af[m], bq[n], acc[2 + m][n], 0, 0, 0);
        __builtin_amdgcn_s_setprio(0);
        BAR();
#pragma unroll
        for (int n = 0; n < 4; ++n) bq[n] = LDB(buf, 1, n);
        af[0] = LDA(buf, 1, 0); af[1] = LDA(buf, 1, 1);
        STG_A(1, nb, t1);
        BAR();
        __builtin_amdgcn_s_setprio(1);
#pragma unroll
        for (int m = 0; m < 2; ++m)
#pragma unroll
            for (int n = 0; n < 4; ++n)
                acc[m][n] = __builtin_amdgcn_mfma_f32_16x16x32_bf16(af[m], bq[n], acc[m][n], 0, 0, 0);
        __builtin_amdgcn_s_setprio(0);
        BAR();
        af[0] = LDA(buf, 1, 2); af[1] = LDA(buf, 1, 3);
        STG_B(1, nb, t1);
        VMCNT3();
        BAR();
        __builtin_amdgcn_s_setprio(1);
#pragma unroll
        for (int m = 0; m < 2; ++m)
#pragma unroll
            for (int n = 0; n < 4; ++n)
                acc[2 + m][n] = __builtin_amdgcn_mfma_f32_16x16x32_bf16(af[m], bq[n], acc[2 + m][n], 0, 0, 0);
        __builtin_amdgcn_s_setprio(0);
        BAR();
    }
    {   // peeled t = 15
        const int buf = 49152;
#pragma unroll
        for (int n = 0; n < 4; ++n) bq[n] = LDB(buf, 0, n);
        af[0] = LDA(buf, 0, 0); af[1] = LDA(buf, 0, 1);
#pragma unroll
        for (int m = 0; m < 2; ++m)
#pragma unroll
            for (int n = 0; n < 4; ++n)
                acc[m][n] = __builtin_amdgcn_mfma_f32_16x16x32_bf16(af[m], bq[n], acc[m][n], 0, 0, 0);
        af[0] = LDA(buf, 0, 2); af[1] = LDA(buf, 0, 3);
#pragma unroll
        for (int m = 0; m < 2; ++m)
#pragma unroll
            for (int n = 0; n < 4; ++n)
                acc[2 + m][n] = __builtin_amdgcn_mfma_f32_16x16x32_bf16(af[m], bq[n], acc[2 + m][n], 0, 0, 0);
        VMCNT0();
        BAR();
#pragma unroll
        for (int n = 0; n < 4; ++n) bq[n] = LDB(buf, 1, n);
        af[0] = LDA(buf, 1, 0); af[1] = LDA(buf, 1, 1);
#pragma unroll
        for (int m = 0; m < 2; ++m)
#pragma unroll
            for (int n = 0; n < 4; ++n)
                acc[m][n] = __builtin_amdgcn_mfma_f32_16x16x32_bf16(af[m], bq[n], acc[m][n], 0, 0, 0);
        af[0] = LDA(buf, 1, 2); af[1] = LDA(buf, 1, 3);
#pragma unroll
        for (int m = 0; m < 2; ++m)
#pragma unroll
            for (int n = 0; n < 4; ++n)
                acc[2 + m][n] = __builtin_amdgcn_mfma_f32_16x16x32_bf16(af[m], bq[n], acc[2 + m][n], 0, 0, 0);
    }
    const int er = lk << 2, ec = lm;
#pragma unroll
    for (int m = 0; m < 4; ++m) {
        int row = m0 + wr * 64 + m * 16 + er;
#pragma unroll
        for (int n = 0; n < 4; ++n) {
            int col = n0 + wc * 64 + n * 16 + ec;
            ushort* cp = C + (size_t)row * ldc + col;
#pragma unroll
            for (int r = 0; r < 4; ++r)
                cp[(size_t)r * ldc] = f2bf(acc[m][n][r] + bias[row + r]);
        }
    }
#undef STG_A
#undef STG_B
#undef LDA
#undef LDB
#undef VMCNT3
#undef VMCNT0
#undef BAR
}

// ---------------------------------------------------------------------------
// 128x128 m97-structure MFMA GEMM (out-projection, bias per col, writes f32)
// ---------------------------------------------------------------------------
__global__ __launch_bounds__(256) void k_gemm_bf16(
    const ushort* __restrict__ A, const ushort* __restrict__ B,
    const float* __restrict__ bias, float* __restrict__ C, int ldc)
{
    __shared__ ushort As[128 * 32];
    __shared__ ushort Bs[128 * 32];
    const int tid  = threadIdx.x;
    const int lane = tid & 63;
    const int w    = tid >> 6;
    const int wm   = (w >> 1) << 6, wn = (w & 1) << 6;
    const int m0   = blockIdx.y << 7, n0 = blockIdx.x << 7;

    f32x4 acc[4][4];
#pragma unroll
    for (int i = 0; i < 4; ++i)
#pragma unroll
        for (int j = 0; j < 4; ++j)
#pragma unroll
            for (int r = 0; r < 4; ++r) acc[i][j][r] = 0.f;

    const char* Ab = (const char*)A + ((size_t)(m0 + (tid >> 2)) << 11) + ((tid & 3) << 4);
    const char* Bb = (const char*)B + ((size_t)(n0 + (tid >> 2)) << 11) + ((tid & 3) << 4);
    char* AsD = (char*)As + tid * 16;
    char* BsD = (char*)Bs + tid * 16;
    const char* ap = (const char*)As + ((wm + (lane & 15)) << 6) + ((lane >> 4) << 4);
    const char* bp = (const char*)Bs + ((wn + (lane & 15)) << 6) + ((lane >> 4) << 4);

    for (int k0 = 0; k0 < 1024; k0 += 32) {
        __syncthreads();
        gload16(AsD,        Ab + k0 * 2);
        gload16(AsD + 4096, Ab + 131072 + k0 * 2);
        gload16(BsD,        Bb + k0 * 2);
        gload16(BsD + 4096, Bb + 131072 + k0 * 2);
        __syncthreads();
        bf16x8 af[4], bfr[4];
#pragma unroll
        for (int i = 0; i < 4; ++i) {
            af[i]  = *(const bf16x8*)(ap + (i << 10));
            bfr[i] = *(const bf16x8*)(bp + (i << 10));
        }
#pragma unroll
        for (int i = 0; i < 4; ++i)
#pragma unroll
            for (int j = 0; j < 4; ++j)
                acc[i][j] = __builtin_amdgcn_mfma_f32_16x16x32_bf16(
                    af[i], bfr[j], acc[i][j], 0, 0, 0);
    }
    const int er = (lane >> 4) << 2;
    const int ec = lane & 15;
#pragma unroll
    for (int i = 0; i < 4; ++i) {
        int row = m0 + wm + (i << 4) + er;
#pragma unroll
        for (int j = 0; j < 4; ++j) {
            int col = n0 + wn + (j << 4) + ec;
            float bz = bias[col];
            float* cp = C + (size_t)row * ldc + col;
#pragma unroll
            for (int r = 0; r < 4; ++r)
                cp[(size_t)r * ldc] = acc[i][j][r] + bz;
        }
    }
}

// ---------------------------------------------------------------------------
// K3a: filter MLP (256 blocks x 16 t)
// ---------------------------------------------------------------------------
__global__ __launch_bounds__(256) void k_filt_mlp(
    const float* __restrict__ z, const float* __restrict__ w0,
    const float* __restrict__ b0, const float* __restrict__ fr,
    const float* __restrict__ w1, const float* __restrict__ b1,
    const float* __restrict__ w2, const float* __restrict__ b2,
    float* __restrict__ H3)
{
    __shared__ float w1t[64 * 65];
    __shared__ float w2t[64 * 65];
    __shared__ float hb[4][64];
    const int tid = threadIdx.x;
    for (int idx = tid; idx < 4096; idx += 256) {
        int j = idx >> 6, m = idx & 63;
        w1t[m*65 + j] = w1[idx];
        w2t[m*65 + j] = w2[idx];
    }
    __syncthreads();
    const int tl = tid >> 6, j = tid & 63;
    const float frj = fr[j];
    const float b0j = b0[j], b1j = b1[j], b2j = b2[j];
    const float w00 = w0[j*3+0], w01 = w0[j*3+1], w02 = w0[j*3+2];
    const int t0 = blockIdx.x * 16;
    for (int r = 0; r < 4; ++r) {
        int t = t0 + r*4 + tl;
        float z0 = z[t*3+0], z1 = z[t*3+1], z2 = z[t*3+2];
        float h = sinf(frj * (b0j + z0*w00 + z1*w01 + z2*w02));
        hb[tl][j] = h;
        __syncthreads();
        float s = b1j;
#pragma unroll
        for (int m = 0; m < 64; ++m) s = fmaf(hb[tl][m], w1t[m*65 + j], s);
        __syncthreads();
        h = sinf(frj * s);
        hb[tl][j] = h;
        __syncthreads();
        s = b2j;
#pragma unroll
        for (int m = 0; m < 64; ++m) s = fmaf(hb[tl][m], w2t[m*65 + j], s);
        h = sinf(frj * s);
        H3[(size_t)t * 64 + j] = h;
        __syncthreads();
    }
}

// ---------------------------------------------------------------------------
// K3b: kf[d][t] = (H3 @ wf^T) * exp-decay
// ---------------------------------------------------------------------------
__global__ __launch_bounds__(256) void k_filt_k(
    const float* __restrict__ H3, const float* __restrict__ wf,
    float* __restrict__ kf)
{
    __shared__ float Hs[64][65];
    __shared__ float Ws[64][65];
    const int tid = threadIdx.x;
    const int t0 = blockIdx.x * 64, d0 = blockIdx.y * 64;
    for (int idx = tid; idx < 4096; idx += 256) {
        int r = idx >> 6, cc = idx & 63;
        Hs[r][cc] = H3[(size_t)(t0 + r) * 64 + cc];
        Ws[r][cc] = wf[(size_t)(d0 + r) * 64 + cc];
    }
    __syncthreads();
    const int tx = tid & 15, ty = tid >> 4;
    float acc[4][4];
#pragma unroll
    for (int i = 0; i < 4; ++i)
#pragma unroll
        for (int jj = 0; jj < 4; ++jj) acc[i][jj] = 0.f;
#pragma unroll
    for (int j = 0; j < 64; ++j) {
        float wv[4], hv[4];
#pragma unroll
        for (int i = 0; i < 4; ++i) wv[i] = Ws[4*ty + i][j];
#pragma unroll
        for (int i = 0; i < 4; ++i) hv[i] = Hs[4*tx + i][j];
#pragma unroll
        for (int i = 0; i < 4; ++i)
#pragma unroll
            for (int jj = 0; jj < 4; ++jj) acc[i][jj] = fmaf(wv[i], hv[jj], acc[i][jj]);
    }
    const float mind = -3.0701134573253944f;
    const float maxd = -15.350567286626972f;
#pragma unroll
    for (int i = 0; i < 4; ++i) {
        int d = d0 + 4*ty + i;
        float delta = fabsf(mind + (maxd - mind) * ((float)d / 1023.f));
#pragma unroll
        for (int jj = 0; jj < 4; ++jj) {
            int t = t0 + 4*tx + jj;
            float tn = (float)t / 4095.f;
            kf[(size_t)d * LL + t] = acc[i][jj] * expf(-tn * delta);
        }
    }
}

// ---------------------------------------------------------------------------
// FFT helpers (8192-pt, radix-4 LDS stages)
// ---------------------------------------------------------------------------
__device__ __forceinline__ int pidx(int p) { return p + (p >> 4); }

__device__ __forceinline__ float2 cmul(float2 a, float2 b) {
    return make_float2(a.x*b.x - a.y*b.y, a.x*b.y + a.y*b.x);
}

__device__ void fft_lds_fwd4(float2* buf, int tid) {
    int lh = 10;
#pragma unroll
    for (int h = 2048; h >= 32; h >>= 2, lh -= 2) {
        const int hh = h >> 1;
        const float rinv = -FPI / (float)h;
        __syncthreads();
#pragma unroll
        for (int r = 0; r < 4; ++r) {
            int bf = (r << 9) + tid;
            int q  = bf & (hh - 1);
            int g  = bf >> lh;
            int j  = (g << (lh + 2)) + q;
            float2 a = buf[pidx(j)];
            float2 b = buf[pidx(j + hh)];
            float2 c = buf[pidx(j + h)];
            float2 d = buf[pidx(j + h + hh)];
            float2 t0 = make_float2(a.x + c.x, a.y + c.y);
            float2 t1 = make_float2(a.x - c.x, a.y - c.y);
            float2 t2 = make_float2(b.x + d.x, b.y + d.y);
            float2 t3 = make_float2(b.y - d.y, d.x - b.x);
            float sn, cs;
            __sincosf(rinv * (float)q, &sn, &cs);
            float c2 = cs*cs - sn*sn, s2 = 2.f*cs*sn;
            float c3 = cs*c2 - sn*s2, s3 = cs*s2 + sn*c2;
            buf[pidx(j)] = make_float2(t0.x + t2.x, t0.y + t2.y);
            float2 e1 = make_float2(t0.x - t2.x, t0.y - t2.y);
            buf[pidx(j + hh)] = make_float2(e1.x*c2 - e1.y*s2, e1.x*s2 + e1.y*c2);
            float2 e2 = make_float2(t1.x + t3.x, t1.y + t3.y);
            buf[pidx(j + h)] = make_float2(e2.x*cs - e2.y*sn, e2.x*sn + e2.y*cs);
            float2 e3 = make_float2(t1.x - t3.x, t1.y - t3.y);
            buf[pidx(j + h + hh)] = make_float2(e3.x*c3 - e3.y*s3, e3.x*s3 + e3.y*c3);
        }
    }
    __syncthreads();
}

__device__ void fft_lds_inv4(float2* buf, int tid) {
    int lh = 4;
#pragma unroll
    for (int h = 32; h <= 2048; h <<= 2, lh += 2) {
        const int hh = h >> 1;
        const float rpos = FPI / (float)h;
        __syncthreads();
#pragma unroll
        for (int r = 0; r < 4; ++r) {
            int bf = (r << 9) + tid;
            int q  = bf & (hh - 1);
            int g  = bf >> lh;
            int j  = (g << (lh + 2)) + q;
            float2 o0 = buf[pidx(j)];
            float2 o1 = buf[pidx(j + hh)];
            float2 o2 = buf[pidx(j + h)];
            float2 o3 = buf[pidx(j + h + hh)];
            float sn, cs;
            __sincosf(rpos * (float)q, &sn, &cs);
            float c2 = cs*cs - sn*sn, s2 = 2.f*cs*sn;
            float c3 = cs*c2 - sn*s2, s3 = cs*s2 + sn*c2;
            float2 p1 = make_float2(o1.x*c2 - o1.y*s2, o1.x*s2 + o1.y*c2);
            float2 p2 = make_float2(o2.x*cs - o2.y*sn, o2.x*sn + o2.y*cs);
            float2 p3 = make_float2(o3.x*c3 - o3.y*s3, o3.x*s3 + o3.y*c3);
            float2 u0 = make_float2(o0.x + p1.x, o0.y + p1.y);
            float2 u1 = make_float2(o0.x - p1.x, o0.y - p1.y);
            float2 u2 = make_float2(p2.x + p3.x, p2.y + p3.y);
            float2 u3 = make_float2(p2.x - p3.x, p2.y - p3.y);
            float2 ib = make_float2(-u3.y, u3.x);
            buf[pidx(j)]          = make_float2(u0.x + u2.x, u0.y + u2.y);
            buf[pidx(j + hh)]     = make_float2(u1.x + ib.x, u1.y + ib.y);
            buf[pidx(j + h)]      = make_float2(u0.x - u2.x, u0.y - u2.y);
            buf[pidx(j + h + hh)] = make_float2(u1.x - ib.x, u1.y - ib.y);
        }
    }
    __syncthreads();
}

__device__ __forceinline__ void fft_reg_fwd(float2* c) {
    const float W16r[8] = {1.f, 0.92387953f, 0.70710678f, 0.38268343f,
                           0.f, -0.38268343f, -0.70710678f, -0.92387953f};
    const float W16i[8] = {0.f, -0.38268343f, -0.70710678f, -0.92387953f,
                           -1.f, -0.92387953f, -0.70710678f, -0.38268343f};
#pragma unroll
    for (int k = 0; k < 8; ++k) {
        float2 a = c[k], b = c[k+8];
        float2 d = make_float2(a.x - b.x, a.y - b.y);
        c[k]   = make_float2(a.x + b.x, a.y + b.y);
        c[k+8] = cmul(d, make_float2(W16r[k], W16i[k]));
    }
    const float W8r[4] = {1.f, 0.70710678f, 0.f, -0.70710678f};
    const float W8i[4] = {0.f, -0.70710678f, -1.f, -0.70710678f};
#pragma unroll
    for (int blk = 0; blk < 16; blk += 8)
#pragma unroll
        for (int k = 0; k < 4; ++k) {
            float2 a = c[blk+k], b = c[blk+k+4];
            float2 d = make_float2(a.x - b.x, a.y - b.y);
            c[blk+k]   = make_float2(a.x + b.x, a.y + b.y);
            c[blk+k+4] = cmul(d, make_float2(W8r[k], W8i[k]));
        }
#pragma unroll
    for (int blk = 0; blk < 16; blk += 4) {
        {   float2 a = c[blk], b = c[blk+2];
            c[blk]   = make_float2(a.x + b.x, a.y + b.y);
            c[blk+2] = make_float2(a.x - b.x, a.y - b.y); }
        {   float2 a = c[blk+1], b = c[blk+3];
            float2 d = make_float2(a.x - b.x, a.y - b.y);
            c[blk+1] = make_float2(a.x + b.x, a.y + b.y);
            c[blk+3] = make_float2(d.y, -d.x); }
    }
#pragma unroll
    for (int blk = 0; blk < 16; blk += 2) {
        float2 a = c[blk], b = c[blk+1];
        c[blk]   = make_float2(a.x + b.x, a.y + b.y);
        c[blk+1] = make_float2(a.x - b.x, a.y - b.y);
    }
}

__device__ __forceinline__ void fft_reg_inv(float2* c) {
#pragma unroll
    for (int blk = 0; blk < 16; blk += 2) {
        float2 a = c[blk], b = c[blk+1];
        c[blk]   = make_float2(a.x + b.x, a.y + b.y);
        c[blk+1] = make_float2(a.x - b.x, a.y - b.y);
    }
#pragma unroll
    for (int blk = 0; blk < 16; blk += 4) {
        {   float2 a = c[blk], b = c[blk+2];
            c[blk]   = make_float2(a.x + b.x, a.y + b.y);
            c[blk+2] = make_float2(a.x - b.x, a.y - b.y); }
        {   float2 a = c[blk+1], b = c[blk+3];
            float2 bt = make_float2(-c[blk+3].y, c[blk+3].x);
            c[blk+1] = make_float2(a.x + bt.x, a.y + bt.y);
            c[blk+3] = make_float2(a.x - bt.x, a.y - bt.y); }
    }
    const float W8r[4] = {1.f, 0.70710678f, 0.f, -0.70710678f};
    const float W8i[4] = {0.f, 0.70710678f, 1.f, 0.70710678f};
#pragma unroll
    for (int blk = 0; blk < 16; blk += 8)
#pragma unroll
        for (int k = 0; k < 4; ++k) {
            float2 a = c[blk+k], b = c[blk+k+4];
            float2 bt = cmul(b, make_float2(W8r[k], W8i[k]));
            c[blk+k]   = make_float2(a.x + bt.x, a.y + bt.y);
            c[blk+k+4] = make_float2(a.x - bt.x, a.y - bt.y);
        }
    const float W16r[8] = {1.f, 0.92387953f, 0.70710678f, 0.38268343f,
                           0.f, -0.38268343f, -0.70710678f, -0.92387953f};
    const float W16i[8] = {0.f, 0.38268343f, 0.70710678f, 0.92387953f,
                           1.f, 0.92387953f, 0.70710678f, 0.38268343f};
#pragma unroll
    for (int k = 0; k < 8; ++k) {
        float2 a = c[k], b = c[k+8];
        float2 bt = cmul(b, make_float2(W16r[k], W16i[k]));
        c[k]   = make_float2(a.x + bt.x, a.y + bt.y);
        c[k+8] = make_float2(a.x - bt.x, a.y - bt.y);
    }
}

// ---------------------------------------------------------------------------
// K4a: kernel spectrum -> fp16x2 (scrambled, pre-scaled by 1/8192)
// ---------------------------------------------------------------------------
__global__ __launch_bounds__(512) void k_kfft(
    const float* __restrict__ kf, f16x2* __restrict__ Kf)
{
    __shared__ float2 buf[8704];
    const int d = blockIdx.x, tid = threadIdx.x;
    const float* krow = kf + (size_t)d * LL;
    const float rinv0 = -FPI / 4096.f;
    for (int i = tid; i < 1024; i += 512) {
        float4 k4 = reinterpret_cast<const float4*>(krow)[i];
        int p = 4 * i;
        float kv[4] = {k4.x, k4.y, k4.z, k4.w};
#pragma unroll
        for (int q = 0; q < 4; ++q) {
            float sn, cs;
            __sincosf(rinv0 * (float)(p + q), &sn, &cs);
            buf[pidx(p + q)]        = make_float2(kv[q], 0.f);
            buf[pidx(p + q + 4096)] = make_float2(kv[q] * cs, kv[q] * sn);
        }
    }
    fft_lds_fwd4(buf, tid);
    float2 c[16];
    const int p0 = tid * 16;
#pragma unroll
    for (int j = 0; j < 16; ++j) c[j] = buf[pidx(p0 + j)];
    fft_reg_fwd(c);
    f16x2* outp = Kf + (size_t)d * 8192 + p0;
#pragma unroll
    for (int j = 0; j < 16; ++j) {
        f16x2 o;
        o[0] = (_Float16)(c[j].x * (1.f/8192.f));
        o[1] = (_Float16)(c[j].y * (1.f/8192.f));
        outp[j] = o;
    }
}

// ---------------------------------------------------------------------------
// conv4: causal 3-tap depthwise conv on a bf16 row, 4 outputs at p..p+3
// ---------------------------------------------------------------------------
__device__ __forceinline__ void conv4(const ushort* __restrict__ row, int p,
    float w0, float w1, float w2, float bias, float* out)
{
    float xm2, xm1;
    if (p >= 2) {
        unsigned prev = *reinterpret_cast<const unsigned*>(row + p - 2);
        xm2 = bf2f((ushort)(prev & 0xffffu));
        xm1 = bf2f((ushort)(prev >> 16));
    } else { xm2 = 0.f; xm1 = 0.f; }
    uint2 cur = *reinterpret_cast<const uint2*>(row + p);
    float x0 = bf2f((ushort)(cur.x & 0xffffu));
    float x1 = bf2f((ushort)(cur.x >> 16));
    float x2 = bf2f((ushort)(cur.y & 0xffffu));
    float x3 = bf2f((ushort)(cur.y >> 16));
    out[0] = fmaf(w2, x0, fmaf(w1, xm1, fmaf(w0, xm2, bias)));
    out[1] = fmaf(w2, x1, fmaf(w1, x0,  fmaf(w0, xm1, bias)));
    out[2] = fmaf(w2, x2, fmaf(w1, x1,  fmaf(w0, x0,  bias)));
    out[3] = fmaf(w2, x3, fmaf(w1, x2,  fmaf(w0, x1,  bias)));
}

// ---------------------------------------------------------------------------
// K4b: per channel d, 3-tap conv of v,x1 from channel-major up2 (bf16),
// gate vin = v*x1, batch-folded FFT conv (z = vin0 + i*vin1) against f16
// spectrum Kf, D*vin skip (vin kept in registers), x0-conv gate, bf16 out.
// ---------------------------------------------------------------------------
__global__ __launch_bounds__(512) void k_fftconv(
    const ushort* __restrict__ up2, const f16x2* __restrict__ Kf,
    const float* __restrict__ sfw, const float* __restrict__ sfb,
    const float* __restrict__ Dp, ushort* __restrict__ yg)
{
    __shared__ float2 buf[8704];
    const int d = blockIdx.x, tid = threadIdx.x;
    const ushort* vrow0  = up2 + (size_t)(2048 + d) * 8192;
    const ushort* vrow1  = vrow0 + 4096;
    const ushort* x1row0 = up2 + (size_t)(1024 + d) * 8192;
    const ushort* x1row1 = x1row0 + 4096;
    const ushort* x0row0 = up2 + (size_t)d * 8192;
    const ushort* x0row1 = x0row0 + 4096;
    const float wv0 = sfw[(2048+d)*3+0], wv1 = sfw[(2048+d)*3+1],
                wv2 = sfw[(2048+d)*3+2], bv = sfb[2048+d];
    const float wx0 = sfw[(1024+d)*3+0], wx1 = sfw[(1024+d)*3+1],
                wx2 = sfw[(1024+d)*3+2], bx = sfb[1024+d];
    const float g0 = sfw[d*3+0], g1 = sfw[d*3+1], g2 = sfw[d*3+2], bg = sfb[d];
    const float rinv0 = -FPI / 4096.f;

    float vs0[8], vs1[8];     // gated conv values, kept live for the D-skip
#pragma unroll
    for (int ii = 0; ii < 2; ++ii) {
        int p = 4 * tid + ii * 2048;
        float cv0[4], cv1[4], cx0[4], cx1[4];
        conv4(vrow0,  p, wv0, wv1, wv2, bv, cv0);
        conv4(vrow1,  p, wv0, wv1, wv2, bv, cv1);
        conv4(x1row0, p, wx0, wx1, wx2, bx, cx0);
        conv4(x1row1, p, wx0, wx1, wx2, bx, cx1);
#pragma unroll
        for (int q = 0; q < 4; ++q) {
            float z0 = cv0[q] * cx0[q];
            float z1 = cv1[q] * cx1[q];
            vs0[ii*4 + q] = z0;
            vs1[ii*4 + q] = z1;
            float sn, cs;
            __sincosf(rinv0 * (float)(p + q), &sn, &cs);
            float2 z = make_float2(z0, z1);
            buf[pidx(p + q)]        = z;
            buf[pidx(p + q + 4096)] = cmul(z, make_float2(cs, sn));
        }
    }
    fft_lds_fwd4(buf, tid);
    float2 c[16];
    const int p0 = tid * 16;
#pragma unroll
    for (int j = 0; j < 16; ++j) c[j] = buf[pidx(p0 + j)];
    fft_reg_fwd(c);
    const f16x2* kfr = Kf + (size_t)d * 8192 + p0;
#pragma unroll
    for (int j = 0; j < 16; ++j) {
        f16x2 kv = kfr[j];
        c[j] = cmul(c[j], make_float2((float)kv[0], (float)kv[1]));
    }
    fft_reg_inv(c);
#pragma unroll
    for (int j = 0; j < 16; ++j) buf[pidx(p0 + j)] = c[j];
    fft_lds_inv4(buf, tid);
    const float Dd = Dp[d];
    ushort* orow0 = yg + (size_t)d * LL;
    ushort* orow1 = yg + ((size_t)DM + d) * LL;
    const float rinv4 = FPI / 4096.f;
#pragma unroll
    for (int ii = 0; ii < 2; ++ii) {
        int p = 4 * tid + ii * 2048;
        float cg0[4], cg1[4];
        conv4(x0row0, p, g0, g1, g2, bg, cg0);
        conv4(x0row1, p, g0, g1, g2, bg, cg1);
        ushort s0[4], s1[4];
#pragma unroll
        for (int q = 0; q < 4; ++q) {
            float sn, cs;
            __sincosf(rinv4 * (float)(p + q), &sn, &cs);
            float2 a  = buf[pidx(p + q)];
            float2 bb = buf[pidx(p + q + 4096)];
            float2 bt = cmul(bb, make_float2(cs, sn));
            s0[q] = f2bf((a.x + bt.x + Dd * vs0[ii*4 + q]) * cg0[q]);
            s1[q] = f2bf((a.y + bt.y + Dd * vs1[ii*4 + q]) * cg1[q]);
        }
        *reinterpret_cast<ushort4*>(orow0 + p) = make_ushort4(s0[0], s0[1], s0[2], s0[3]);
        *reinterpret_cast<ushort4*>(orow1 + p) = make_ushort4(s1[0], s1[1], s1[2], s1[3]);
    }
}

// ---------------------------------------------------------------------------
// K_tr: yg[b][d][t] (bf16) -> Ag[b][t][d] (bf16), 64x64 LDS tiles
// ---------------------------------------------------------------------------
__global__ __launch_bounds__(256) void k_tr(
    const ushort* __restrict__ yg, ushort* __restrict__ Ag)
{
    __shared__ ushort S[64][72];
    const int b  = blockIdx.z;
    const int d0 = blockIdx.y * 64;
    const int t0 = blockIdx.x * 64;
    const int tid = threadIdx.x;
#pragma unroll
    for (int p = 0; p < 2; ++p) {
        int idx = p * 256 + tid;
        int dr = idx >> 3, c8 = (idx & 7) << 3;
        uint4 v = *reinterpret_cast<const uint4*>(
            yg + ((size_t)b * DM + d0 + dr) * LL + t0 + c8);
        *reinterpret_cast<uint4*>(&S[dr][c8]) = v;
    }
    __syncthreads();
#pragma unroll
    for (int p = 0; p < 2; ++p) {
        int idx = p * 256 + tid;
        int tr = idx >> 3, dq = (idx & 7) << 3;
        ushort tmp[8] __attribute__((aligned(16)));
#pragma unroll
        for (int q = 0; q < 8; ++q) tmp[q] = S[dq + q][tr];
        *reinterpret_cast<uint4*>(Ag + ((size_t)b * LL + t0 + tr) * DM + d0 + dq) =
            *reinterpret_cast<uint4*>(tmp);
    }
}

// ---------------------------------------------------------------------------
extern "C" void kernel_launch(void* const* d_in, const int* in_sizes, int n_in,
                              void* d_out, int out_size, void* d_ws, size_t ws_size,
                              hipStream_t stream)
{
    if (n_in < 17) return;
    const float* u    = (const float*)d_in[0];
    const float* w_in = (const float*)d_in[1];
    const float* b_in = (const float*)d_in[2];
    const float* sf_w = (const float*)d_in[3];
    const float* sf_b = (const float*)d_in[4];
    const float* z    = (const float*)d_in[5];
    const float* w0   = (const float*)d_in[6];
    const float* b0   = (const float*)d_in[7];
    const float* freq = (const float*)d_in[8];
    const float* w1   = (const float*)d_in[9];
    const float* b1   = (const float*)d_in[10];
    const float* w2   = (const float*)d_in[11];
    const float* b2   = (const float*)d_in[12];
    const float* wf   = (const float*)d_in[13];
    const float* Dp   = (const float*)d_in[14];
    const float* wout = (const float*)d_in[15];
    const float* bout = (const float*)d_in[16];
    float* out = (float*)d_out;
    float* ws  = (float*)d_ws;

    // Overlaid workspace (float offsets):
    //  [0, 12582912)           up2 bf16 [3072][8192] (P2-P6)
    //  [16777216, +4194304)    kf f32 (P4-P5) -> yg bf16 (P6-P7)
    //  [20971520, +4194304)    H3 f32 (P3-P4) -> Ag bf16 (P7-P8)
    //  [25165824, +4194304)    ub bf16 (P1-P2)
    //  [33554432, +8388608)    wb bf16 (P1-P2) -> Kf f16x2 (P5-P6)
    //  [41943040, +524288)     woutb bf16 (P1-P8)
    ushort* up2   = (ushort*)ws;
    float*  kfbuf = ws + 16777216;
    ushort* yg    = (ushort*)(ws + 16777216);
    float*  H3    = ws + 20971520;
    ushort* Ag    = (ushort*)(ws + 20971520);
    ushort* ub    = (ushort*)(ws + 25165824);
    ushort* wb    = (ushort*)(ws + 33554432);
    f16x2*  Kf    = (f16x2*)(ws + 33554432);
    ushort* woutb = (ushort*)(ws + 41943040);
    const size_t NEED = (size_t)(41943040 + 524288) * 4;
    if (ws_size < NEED) return;

    hipLaunchKernelGGL(k_cvt3,     dim3(2048), dim3(256), 0, stream,
                       u, ub, 2097152, w_in, wb, 786432, wout, woutb, 262144);
    hipLaunchKernelGGL(k_gemm128n, dim3((E3/128) * (8192/256)), dim3(512), 0, stream,
                       wb, ub, b_in, up2, 8192/256, 8192);
    hipLaunchKernelGGL(k_filt_mlp, dim3(LL/16), dim3(256), 0, stream,
                       z, w0, b0, freq, w1, b1, w2, b2, H3);
    hipLaunchKernelGGL(k_filt_k,   dim3(LL/64, DM/64), dim3(256), 0, stream,
                       H3, wf, kfbuf);
    hipLaunchKernelGGL(k_kfft,     dim3(DM), dim3(512), 0, stream,
                       kfbuf, Kf);
    hipLaunchKernelGGL(k_fftconv,  dim3(DM), dim3(512), 0, stream,
                       up2, Kf, sf_w, sf_b, Dp, yg);
    hipLaunchKernelGGL(k_tr,       dim3(LL/64, DM/64, NB), dim3(256), 0, stream,
                       yg, Ag);
    hipLaunchKernelGGL(k_gemm_bf16, dim3(DM/128, 8192/128), dim3(256), 0, stream,
                       Ag, woutb, bout, out, DM);
}